// Round 3
// baseline (123.912 us; speedup 1.0000x reference)
//
#include <hip/hip_runtime.h>
#include <hip/hip_bf16.h>

// Positional encoder: per input element e, 20 outputs: [sin(x*2^0..9), cos(x*2^0..9)].
// Memory-bound (24 MB read, 480 MB write). One thread per OUTPUT float4 (5 quads
// per element). cos(2*pi*r) == sin(2*pi*(r + 0.25)) -- 0.25 is exact in fp32, so
// every output is a single v_fract + v_sin (input in revolutions). No LDS, no
// barrier, perfectly coalesced 16B stores.

#define ENC_BLOCK 320   // 5 waves; 30M quads / 320 = 93750 blocks exactly at N=2M

__global__ __launch_bounds__(ENC_BLOCK)
void Encoder_65077344469353_kernel(const float* __restrict__ x,
                                   float* __restrict__ out,
                                   int n_elem) {
    const long long nq = (long long)n_elem * 5;                 // total float4s
    const long long g  = (long long)blockIdx.x * ENC_BLOCK + threadIdx.x;
    if (g >= nq) return;

    const unsigned g32 = (unsigned)g;        // < 30M, 32-bit divide is cheaper
    const unsigned e   = g32 / 5u;           // input element index
    const int      q   = (int)(g32 - e * 5u);// quad-within-element, 0..4

    const float INV2PI = 0.15915494309189535f;
    const float rv = x[e] * INV2PI;          // phase in revolutions at d=0

    float v[4];
    #pragma unroll
    for (int i = 0; i < 4; ++i) {
        const int s   = q * 4 + i;           // output slot 0..19
        const int isc = (s >= 10) ? 1 : 0;   // cos half?
        const int d   = s - 10 * isc;        // frequency exponent 0..9
        const float sc  = __uint_as_float((unsigned)(127 + d) << 23); // 2^d exact
        const float off = isc ? 0.25f : 0.0f;                         // quarter rev
        const float r = __builtin_amdgcn_fractf(__builtin_fmaf(rv, sc, off));
        v[i] = __builtin_amdgcn_sinf(r);     // sin(2*pi*r)
    }

    float4 o; o.x = v[0]; o.y = v[1]; o.z = v[2]; o.w = v[3];
    reinterpret_cast<float4*>(out)[g] = o;   // coalesced dwordx4
}

extern "C" void kernel_launch(void* const* d_in, const int* in_sizes, int n_in,
                              void* d_out, int out_size, void* d_ws, size_t ws_size,
                              hipStream_t stream) {
    const float* x = (const float*)d_in[0];
    float* out = (float*)d_out;
    const int n_elem = in_sizes[0];                       // N*3 = 6,000,000
    const long long nq = (long long)n_elem * 5;           // 30,000,000 quads
    const int blocks = (int)((nq + ENC_BLOCK - 1) / ENC_BLOCK);
    Encoder_65077344469353_kernel<<<dim3(blocks), dim3(ENC_BLOCK), 0, stream>>>(
        x, out, n_elem);
}

// Round 4
// 88.233 us; speedup vs baseline: 1.4044x; 1.4044x over previous
//
#include <hip/hip_runtime.h>
#include <hip/hip_bf16.h>

// Positional encoder: per input element e, 20 outputs [sin(x*2^0..9), cos(x*2^0..9)].
// Memory-bound: 24 MB read + 480 MB write. Mapping: one thread per OUTPUT float4
// (slot quad q=0..4 of element e), so stores are perfectly coalesced dwordx4.
// Grid-stride with total threads divisible by 5 => q is loop-invariant: the
// slot->(scale,offset) table is hoisted; steady-state body is
// load + fma + 4x(fract+sin) + nontemporal store. cos(2*pi*r)=sin(2*pi*(r+0.25)).

#define ENC_BLOCK 256
#define ENC_GRID  1280              // 5 blocks/CU co-resident; 1280*256 = 327,680 ≡ 0 (mod 5)

__global__ __launch_bounds__(ENC_BLOCK)
void Encoder_65077344469353_kernel(const float* __restrict__ x,
                                   float* __restrict__ out,
                                   int n_elem) {
    typedef float f4 __attribute__((ext_vector_type(4)));
    const unsigned nq    = (unsigned)n_elem * 5u;      // 30,000,000 quads
    const unsigned T     = ENC_BLOCK * ENC_GRID;       // 327,680 threads
    const unsigned estep = T / 5u;                     // 65,536 elements per sweep

    unsigned g = blockIdx.x * ENC_BLOCK + threadIdx.x;
    const unsigned q = g % 5u;                         // loop-invariant quad id
    unsigned e = g / 5u;

    // Hoisted per-thread constants: r_i = fract(x * sc[i] + off[i]); out = sin(2*pi*r_i)
    float sc[4], off[4];
    #pragma unroll
    for (int i = 0; i < 4; ++i) {
        const int s   = (int)(q * 4u) + i;             // output slot 0..19
        const int isc = (s >= 10) ? 1 : 0;             // cos half
        const int d   = s - 10 * isc;                  // frequency exponent 0..9
        // 2^d * (1/2pi): exact power-of-2 scaling of the rounded 1/2pi
        sc[i]  = __uint_as_float((unsigned)(127 + d) << 23) * 0.15915494309189535f;
        off[i] = isc ? 0.25f : 0.0f;                   // quarter revolution
    }

    f4* __restrict__ out4 = (f4*)out;
    for (; g < nq; g += T, e += estep) {
        const float xv = x[e];                         // 5 lanes/cacheline dedup'd
        f4 o;
        o.x = __builtin_amdgcn_sinf(__builtin_amdgcn_fractf(__builtin_fmaf(xv, sc[0], off[0])));
        o.y = __builtin_amdgcn_sinf(__builtin_amdgcn_fractf(__builtin_fmaf(xv, sc[1], off[1])));
        o.z = __builtin_amdgcn_sinf(__builtin_amdgcn_fractf(__builtin_fmaf(xv, sc[2], off[2])));
        o.w = __builtin_amdgcn_sinf(__builtin_amdgcn_fractf(__builtin_fmaf(xv, sc[3], off[3])));
        __builtin_nontemporal_store(o, out4 + g);      // streaming 16B store
    }
}

extern "C" void kernel_launch(void* const* d_in, const int* in_sizes, int n_in,
                              void* d_out, int out_size, void* d_ws, size_t ws_size,
                              hipStream_t stream) {
    const float* x = (const float*)d_in[0];
    float* out = (float*)d_out;
    const int n_elem = in_sizes[0];                    // N*3 = 6,000,000
    Encoder_65077344469353_kernel<<<dim3(ENC_GRID), dim3(ENC_BLOCK), 0, stream>>>(
        x, out, n_elem);
}